// Round 5
// baseline (1502.366 us; speedup 1.0000x reference)
//
#include <hip/hip_runtime.h>

// Problem constants (match reference setup_inputs)
constexpr int NN = 50000;        // nodes
constexpr int NE = 1600000;      // edges
constexpr int NB = 8;            // batch
constexpr int M_ROWS = NN * NB;  // 400000 flattened rows (m = b*NN + n)
constexpr int SLAB = NN * 64;    // 3,200,000 B: one 64-B feature-slice of all nodes

typedef unsigned short ushort;
typedef unsigned int uint;
typedef unsigned char uchar;
typedef float f32x2v __attribute__((ext_vector_type(2)));
typedef float f32x4v __attribute__((ext_vector_type(4)));
typedef uint u32x4 __attribute__((ext_vector_type(4)));
typedef uint u32x2 __attribute__((ext_vector_type(2)));
typedef uint u32x4a __attribute__((ext_vector_type(4), aligned(4)));
typedef float f32x4a __attribute__((ext_vector_type(4), aligned(4)));

__device__ __forceinline__ ushort f2bf(float f) {
  union { float f; uint u; } v;
  v.f = f;
  const uint r = v.u + 0x7fffu + ((v.u >> 16) & 1u);  // RNE
  return (ushort)(r >> 16);
}
__device__ __forceinline__ float bfhi(uint g) {
  union { uint u; float f; } v;
  v.u = g & 0xffff0000u;
  return v.f;
}
__device__ __forceinline__ float bflo(uint g) {
  union { uint u; float f; } v;
  v.u = g << 16;
  return v.f;
}

// ---- fp8 e4m3fn -> 2x f32x2 (HW cvt; exact manual fallback) ----
__device__ __forceinline__ void fp8x4_to_f32x2(uint v, f32x2v& lo, f32x2v& hi) {
#if __has_builtin(__builtin_amdgcn_cvt_pk_f32_fp8)
  lo = __builtin_amdgcn_cvt_pk_f32_fp8((int)v, false);
  hi = __builtin_amdgcn_cvt_pk_f32_fp8((int)v, true);
#else
  union { _Float16 h; ushort u; } c0, c1, c2, c3;
  c0.u = (ushort)(((v & 0x80u) << 8) | ((v & 0x7fu) << 7));
  c1.u = (ushort)(((v & 0x8000u)) | ((v & 0x7f00u) >> 1));
  c2.u = (ushort)((((v >> 16) & 0x80u) << 8) | (((v >> 16) & 0x7fu) << 7));
  c3.u = (ushort)((((v >> 24) & 0x80u) << 8) | (((v >> 24) & 0x7fu) << 7));
  lo.x = (float)c0.h * 256.0f;
  lo.y = (float)c1.h * 256.0f;
  hi.x = (float)c2.h * 256.0f;
  hi.y = (float)c3.h * 256.0f;
#endif
}
__device__ __forceinline__ uint f32_to_fp8(float x) {
#if __has_builtin(__builtin_amdgcn_cvt_pk_fp8_f32)
  return (uint)__builtin_amdgcn_cvt_pk_fp8_f32(x, x, 0, false) & 0xffu;
#else
  union { _Float16 h; ushort u; } c;
  c.h = (_Float16)(x * (1.0f / 256.0f));
  const uint h = c.u;
  uint r = h & 0x7fffu;
  r = (r + 0x3Fu + ((r >> 7) & 1u)) >> 7;  // RNE f16 -> e4m3 (scaled)
  if (r > 0x7Eu) r = 0x7Eu;                // saturate to 448
  return ((h >> 8) & 0x80u) | r;
#endif
}

// ---------------------------------------------------------------------------
// CSR row_ptr from sorted edge_rows via per-row binary search (lower_bound).
// ---------------------------------------------------------------------------
__global__ __launch_bounds__(256) void rowptr_kernel(const int* __restrict__ rows,
                                                     int* __restrict__ row_ptr) {
  const int r = blockIdx.x * 256 + threadIdx.x;
  if (r > NN) return;
  int lo = 0, hi = NE;
  while (lo < hi) {
    const int mid = (lo + hi) >> 1;
    if (rows[mid] < r) lo = mid + 1;
    else hi = mid;
  }
  row_ptr[r] = lo;
}

// ---------------------------------------------------------------------------
// W [128][DOUT] fp32 -> Wt [DOUT][128] bf16 (tiny, once per launch).
// ---------------------------------------------------------------------------
__global__ __launch_bounds__(256) void wtrans_kernel(const float* __restrict__ W,
                                                     ushort* __restrict__ Wt,
                                                     int dout) {
  const int idx = blockIdx.x * 256 + threadIdx.x;
  if (idx >= dout * 128) return;
  const int n = idx >> 7;
  const int k = idx & 127;
  Wt[idx] = f2bf(W[k * dout + n]);
}

// ---------------------------------------------------------------------------
// MFMA GEMM: S (fp8 e4m3, slice-contiguous) = A[M][128] @ Wt^T.
// A fp32 (ABF16=0) or bf16. Block = 256 thr = 4 waves.
// Ws staged in LDS ONCE per block (round-1/3: global-B and reg-resident-W
// both slower).  RT=5 row-tiles (320 rows) per block.
// S layout (NEW): slice-contiguous for the sliced spmm:
//   gcol = b*DOUT + col  in [0, NB*DOUT);  slice = gcol/64; inner = gcol%64;
//   S[slice*SLAB + n*64 + inner].   Each slice = 3.2 MB contiguous.
// Epilogue via byte-LDS for coalesced 16B stores (16 | 64 so chunks never
// cross a slice boundary).
// ---------------------------------------------------------------------------
template <int DOUT, bool ABF16>
__global__ __launch_bounds__(256) void gemm_mfma(const void* __restrict__ Av,
                                                 const ushort* __restrict__ Wt,
                                                 uchar* __restrict__ S) {
  constexpr int NT = DOUT / 16;
  constexpr int RT = 5;               // row-tiles per block (320 rows)
  constexpr int LDK = 136;            // bf16 LDS row stride
  constexpr int LB = DOUT + 16;       // byte-epilogue row stride
  typedef __attribute__((ext_vector_type(8))) short bf16x8;
  typedef __attribute__((ext_vector_type(4))) float f32x4;

  __shared__ ushort As[64 * LDK];     // reused as byte buffer in epilogue
  __shared__ ushort Ws[DOUT * LDK];

  const int t = threadIdx.x;
  const int w = t >> 6;
  const int l = t & 63;

  // ---- stage Wt: DOUT x 128 bf16 -> LDS (once per block) ----
#pragma unroll
  for (int q = 0; q < (DOUT * 128) / (8 * 256); q++) {
    const int chunk = t + q * 256;
    const int n = chunk >> 4;
    const int off = (chunk & 15) * 8;
    *(uint4*)(Ws + n * LDK + off) = *(const uint4*)(Wt + n * 128 + off);
  }

  const int mrow = w * 16 + (l & 15);
  const int q8 = (l >> 4) * 8;

  for (int rt = 0; rt < RT; rt++) {
    const size_t m0 = (size_t)blockIdx.x * (64 * RT) + (size_t)rt * 64;

    // ---- stage A tile: 64 rows x 128 -> bf16 LDS ----
    if constexpr (ABF16) {
      const ushort* A = (const ushort*)Av;
#pragma unroll
      for (int q = 0; q < 4; q++) {
        const int chunk = t + q * 256;
        const int row = chunk >> 4;
        const int off = (chunk & 15) * 8;
        *(u32x4*)(As + row * LDK + off) =
            __builtin_nontemporal_load((const u32x4*)(A + (m0 + row) * 128 + off));
      }
    } else {
      const float* A = (const float*)Av;
      const int row = t >> 2;
      const int c0 = (t & 3) * 32;
      const float* src = A + (m0 + row) * 128 + c0;
      ushort* dst = As + row * LDK + c0;
#pragma unroll
      for (int q = 0; q < 8; q++) {
        const f32x4v g = __builtin_nontemporal_load((const f32x4v*)(src + q * 4));
        u32x2 p;
        p.x = (uint)f2bf(g.x) | ((uint)f2bf(g.y) << 16);
        p.y = (uint)f2bf(g.z) | ((uint)f2bf(g.w) << 16);
        *(u32x2*)(dst + q * 4) = p;  // one ds_write_b64 instead of 4x b16
      }
    }
    __syncthreads();

    bf16x8 a[4];
    const ushort* ap = As + mrow * LDK + q8;
#pragma unroll
    for (int ks = 0; ks < 4; ks++) a[ks] = *(const bf16x8*)(ap + ks * 32);

    f32x4 acc[NT];
#pragma unroll
    for (int nt = 0; nt < NT; nt++) acc[nt] = (f32x4)0.f;

#pragma unroll
    for (int nt = 0; nt < NT; nt++) {
      const ushort* bp = Ws + (nt * 16 + (l & 15)) * LDK + q8;
#pragma unroll
      for (int ks = 0; ks < 4; ks++) {
        const bf16x8 b = *(const bf16x8*)(bp + ks * 32);
        acc[nt] =
            __builtin_amdgcn_mfma_f32_16x16x32_bf16(a[ks], b, acc[nt], 0, 0, 0);
      }
    }

    // ---- epilogue: acc -> fp8 byte-LDS -> packed 16B global stores ----
    __syncthreads();
    uchar* Ab = (uchar*)As;
    const int erow = w * 16 + (l >> 4) * 4;
    const int ecol = l & 15;
#pragma unroll
    for (int nt = 0; nt < NT; nt++)
#pragma unroll
      for (int r = 0; r < 4; r++)
        Ab[(erow + r) * LB + nt * 16 + ecol] = (uchar)f32_to_fp8(acc[nt][r]);
    __syncthreads();

#pragma unroll
    for (int q = 0; q < (64 * DOUT) / (16 * 256); q++) {
      const int chunk = t + q * 256;
      const int row = chunk / (DOUT / 16);
      const int off = (chunk % (DOUT / 16)) * 16;
      const uint4 v = *(const uint4*)(Ab + row * LB + off);
      const int m = (int)m0 + row;
      const int b = m / NN;
      const int n = m - b * NN;
      const int gcol = b * DOUT + off;
      *(uint4*)(S + (size_t)(gcol >> 6) * SLAB + (size_t)n * 64 + (gcol & 63)) = v;
    }
    __syncthreads();  // Ab (=As) is re-staged next iteration
  }
}

// ---------------------------------------------------------------------------
// Feature-sliced SpMM over fp8 S (slice-contiguous layout).
// slice = 64 B of a node's flattened (batch*feat) group -> 16 slices @3.2 MB
// (layers 1/2), 8 slices (layer 3).  One wave per (row, slice); each
// quad-of-16-lanes handles one edge's 64 B; 4 edges per wave-step with
// per-quad contiguous dwordx4 col/val loads.  Quad-partitioned accumulation,
// reduced at the end with shfl_xor(16/32).
// XCD PINNING: slice = bid%8 (+8 in phase 2) rides the measured round-robin
// bid->XCD mapping, so each XCD gathers from a RESIDENT 3.2 MB L2 region.
// Performance-only assumption; correctness never depends on it.
// RMODE: 0 none, 1 fp32, 2 bf16 resid.  SPB = slices per batch (D = SPB*64).
// ---------------------------------------------------------------------------
template <int SLICES, int SPB, int RMODE, bool SIGMOID, bool OBF16>
__global__ __launch_bounds__(256) void spmm_sliced(
    const uchar* __restrict__ S, const int* __restrict__ row_ptr,
    const int* __restrict__ cols, const float* __restrict__ vals,
    const float* __restrict__ bias, const void* resid, void* out) {
  constexpr int D = SPB * 64;
  constexpr int PER_PHASE = (NN / 4) * 8;

  const int wave = threadIdx.x >> 6;
  const int lane = threadIdx.x & 63;
  const int q = lane >> 4;
  const int qi = lane & 15;

  const int bid = blockIdx.x;
  const int phase = bid / PER_PHASE;
  const int within = bid - phase * PER_PHASE;
  const int slice = phase * 8 + (within & 7);  // XCD-pinned via bid%8
  const int rc = within >> 3;
  const int r = __builtin_amdgcn_readfirstlane(rc * 4 + wave);

  const uint vbase = (uint)slice * (uint)SLAB + (uint)(qi * 4);

  f32x2v a01 = {0.f, 0.f};
  f32x2v a23 = {0.f, 0.f};

  const int e0 = __builtin_amdgcn_readfirstlane(row_ptr[r]);
  const int e1 = __builtin_amdgcn_readfirstlane(row_ptr[r + 1]);

  int e = e0;
  // ---- main: 16-edge chunks; quad q owns edges [e+4q, e+4q+4) ----
  for (; e + 16 <= e1; e += 16) {
    const int eq = e + q * 4;
    const u32x4a cc = *(const u32x4a*)(cols + eq);
    const f32x4a ww = *(const f32x4a*)(vals + eq);
    uint g0 = *(const uint*)(S + ((cc.x << 6) + vbase));
    uint g1 = *(const uint*)(S + ((cc.y << 6) + vbase));
    uint g2 = *(const uint*)(S + ((cc.z << 6) + vbase));
    uint g3 = *(const uint*)(S + ((cc.w << 6) + vbase));
    f32x2v lo, hi;
    fp8x4_to_f32x2(g0, lo, hi);
    f32x2v w2 = {ww.x, ww.x};
    a01 = __builtin_elementwise_fma(w2, lo, a01);
    a23 = __builtin_elementwise_fma(w2, hi, a23);
    fp8x4_to_f32x2(g1, lo, hi);
    w2.x = ww.y; w2.y = ww.y;
    a01 = __builtin_elementwise_fma(w2, lo, a01);
    a23 = __builtin_elementwise_fma(w2, hi, a23);
    fp8x4_to_f32x2(g2, lo, hi);
    w2.x = ww.z; w2.y = ww.z;
    a01 = __builtin_elementwise_fma(w2, lo, a01);
    a23 = __builtin_elementwise_fma(w2, hi, a23);
    fp8x4_to_f32x2(g3, lo, hi);
    w2.x = ww.w; w2.y = ww.w;
    a01 = __builtin_elementwise_fma(w2, lo, a01);
    a23 = __builtin_elementwise_fma(w2, hi, a23);
  }
  // ---- tail (<=15 edges): clamped per-lane loads, zero weights for pad ----
  if (e < e1) {
    const int eqt = e + q * 4;
#pragma unroll
    for (int k = 0; k < 4; k++) {
      const int idx = eqt + k;
      const int cidx = idx < e1 ? idx : e1 - 1;
      const uint cv = (uint)cols[cidx];
      const float wk = idx < e1 ? vals[cidx] : 0.f;
      const uint g = *(const uint*)(S + ((cv << 6) + vbase));
      f32x2v lo, hi;
      fp8x4_to_f32x2(g, lo, hi);
      const f32x2v w2 = {wk, wk};
      a01 = __builtin_elementwise_fma(w2, lo, a01);
      a23 = __builtin_elementwise_fma(w2, hi, a23);
    }
  }

  // ---- quad reduce: lanes qi, qi+16, qi+32, qi+48 hold channel partials ----
  float a0 = a01.x, a1 = a01.y, a2 = a23.x, a3 = a23.y;
  a0 += __shfl_xor(a0, 16); a0 += __shfl_xor(a0, 32);
  a1 += __shfl_xor(a1, 16); a1 += __shfl_xor(a1, 32);
  a2 += __shfl_xor(a2, 16); a2 += __shfl_xor(a2, 32);
  a3 += __shfl_xor(a3, 16); a3 += __shfl_xor(a3, 32);

  if (q == 0) {
    const int b = slice / SPB;
    const int f0 = (slice - b * SPB) * 64 + qi * 4;
    const size_t orow = ((size_t)b * NN + r) * D + f0;
    const f32x4v bb = *(const f32x4v*)(bias + f0);
    a0 += bb.x;
    a1 += bb.y;
    a2 += bb.z;
    a3 += bb.w;
    if constexpr (RMODE == 1) {
      const f32x4v res =
          __builtin_nontemporal_load((const f32x4v*)((const float*)resid + orow));
      a0 += res.x;
      a1 += res.y;
      a2 += res.z;
      a3 += res.w;
    } else if constexpr (RMODE == 2) {
      const u32x2 g =
          __builtin_nontemporal_load((const u32x2*)((const ushort*)resid + orow));
      a0 += bflo(g.x);
      a1 += bfhi(g.x);
      a2 += bflo(g.y);
      a3 += bfhi(g.y);
    }
    a0 = fmaxf(a0, 0.f);
    a1 = fmaxf(a1, 0.f);
    a2 = fmaxf(a2, 0.f);
    a3 = fmaxf(a3, 0.f);
    if constexpr (SIGMOID) {
      a0 = 1.f / (1.f + __expf(-a0));
      a1 = 1.f / (1.f + __expf(-a1));
      a2 = 1.f / (1.f + __expf(-a2));
      a3 = 1.f / (1.f + __expf(-a3));
    }
    if constexpr (OBF16) {
      u32x2 o;
      o.x = (uint)f2bf(a0) | ((uint)f2bf(a1) << 16);
      o.y = (uint)f2bf(a2) | ((uint)f2bf(a3) << 16);
      __builtin_nontemporal_store(o, (u32x2*)((ushort*)out + orow));
    } else {
      f32x4v o;
      o.x = a0;
      o.y = a1;
      o.z = a2;
      o.w = a3;
      __builtin_nontemporal_store(o, (f32x4v*)((float*)out + orow));
    }
  }
}

// ---------------------------------------------------------------------------
// Launch. ws: row_ptr(0x40000) | Wt1(0x48000) | Wt2(0x50000) | Wt3(0x54000)
// | S fp8 slice-contiguous 51.2 MB (0x60000) | H bf16 102.4 MB.  ~154 MB.
// ---------------------------------------------------------------------------
extern "C" void kernel_launch(void* const* d_in, const int* in_sizes, int n_in,
                              void* d_out, int out_size, void* d_ws, size_t ws_size,
                              hipStream_t stream) {
  const float* x = (const float*)d_in[0];
  const int* erows = (const int*)d_in[1];
  const int* ecols = (const int*)d_in[2];
  const float* evals = (const float*)d_in[3];
  const float* W1 = (const float*)d_in[4];
  const float* b1 = (const float*)d_in[5];
  const float* W2 = (const float*)d_in[6];
  const float* b2 = (const float*)d_in[7];
  const float* W3 = (const float*)d_in[8];
  const float* b3 = (const float*)d_in[9];

  char* ws = (char*)d_ws;
  int* row_ptr = (int*)ws;
  ushort* Wt1 = (ushort*)(ws + 0x40000);
  ushort* Wt2 = (ushort*)(ws + 0x48000);
  ushort* Wt3 = (ushort*)(ws + 0x50000);
  uchar* Sf8 = (uchar*)(ws + 0x60000);
  ushort* H = (ushort*)(ws + 0x60000 + (size_t)M_ROWS * 128);

  rowptr_kernel<<<(NN + 256) / 256, 256, 0, stream>>>(erows, row_ptr);
  wtrans_kernel<<<(128 * 128) / 256, 256, 0, stream>>>(W1, Wt1, 128);
  wtrans_kernel<<<(128 * 128) / 256, 256, 0, stream>>>(W2, Wt2, 128);
  wtrans_kernel<<<(64 * 128) / 256, 256, 0, stream>>>(W3, Wt3, 64);

  constexpr int GB = M_ROWS / (64 * 5);  // 1250 blocks (RT=5)

  // Layer 1: S = x@W1 (16 slices); H = relu(spmm(S) + b1 + x)
  gemm_mfma<128, false><<<GB, 256, 0, stream>>>(x, Wt1, Sf8);
  spmm_sliced<16, 2, 1, false, true><<<(NN / 4) * 16, 256, 0, stream>>>(
      Sf8, row_ptr, ecols, evals, b1, x, H);
  // Layer 2: S = H@W2 (16 slices); H = relu(spmm(S) + b2 + H)
  gemm_mfma<128, true><<<GB, 256, 0, stream>>>(H, Wt2, Sf8);
  spmm_sliced<16, 2, 2, false, true><<<(NN / 4) * 16, 256, 0, stream>>>(
      Sf8, row_ptr, ecols, evals, b2, H, H);
  // Layer 3: S = H@W3 (8 slices); out = sigmoid(relu(spmm(S) + b3))
  gemm_mfma<64, true><<<GB, 256, 0, stream>>>(H, Wt3, Sf8);
  spmm_sliced<8, 1, 0, true, false><<<(NN / 4) * 8, 256, 0, stream>>>(
      Sf8, row_ptr, ecols, evals, b3, nullptr, (float*)d_out);
}